// Round 18
// baseline (198.280 us; speedup 1.0000x reference)
//
#include <hip/hip_runtime.h>
#include <hip/hip_fp16.h>
#include <math.h>

static constexpr int N = 50000;    // < 65536 -> src fits u16
static constexpr int E = 800000;
static constexpr int D = 128;      // D_IN = D_HID
static constexpr int DO = 64;      // D_OUT
static constexpr int CAP = 64;     // ELL row capacity (Poisson(16); P(deg>64) ~ 1e-26)
static constexpr int NXCD = 8;
static constexpr int DPX = 6272;   // dst range per XCD slot (8*6272 >= N)
static constexpr int CHUNK = 2048; // edges per workgroup chunk

// ---- bf16 helpers ----
__device__ __forceinline__ unsigned pack_bf16(float a, float b) {
  unsigned ua = __float_as_uint(a), ub = __float_as_uint(b);
  ua = (ua + 0x7FFFu + ((ua >> 16) & 1u)) >> 16;
  ub = (ub + 0x7FFFu + ((ub >> 16) & 1u)) >> 16;
  return ua | (ub << 16);
}
__device__ __forceinline__ float blo(unsigned u) { return __uint_as_float(u << 16); }
__device__ __forceinline__ float bhi(unsigned u) { return __uint_as_float(u & 0xFFFF0000u); }

// ---- ELL entry: low16 = src (u16), high16 = fp16 bits of raw ew ----
__device__ __forceinline__ unsigned ell_pack(int s, float w) {
  return (unsigned)s | ((unsigned)__half_as_ushort(__float2half(w)) << 16);
}
__device__ __forceinline__ float ell_w(unsigned p) {
  return __half2float(__ushort_as_half((unsigned short)(p >> 16)));
}

typedef __attribute__((ext_vector_type(8))) short bf16x8;
typedef __attribute__((ext_vector_type(4))) float f32x4;

// ---------------- zero per-dst counters ----------------
__global__ __launch_bounds__(256) void k_zero(int* __restrict__ cnt) {
  int i = blockIdx.x * 256 + threadIdx.x;
  if (i < N) cnt[i] = 0;
}

// ---------------- XCD-partitioned ELL build (R17, kept) ----------------
__global__ __launch_bounds__(256) void k_build_ell(const int* __restrict__ src,
                                                   const int* __restrict__ dst,
                                                   const float* __restrict__ ew,
                                                   int* __restrict__ cnt,
                                                   unsigned* __restrict__ ell) {
  const int xcd = blockIdx.x & (NXCD - 1);
  const int base = (blockIdx.x >> 3) * CHUNK;
  const int dlo = xcd * DPX, dhi = dlo + DPX;
#pragma unroll
  for (int i = 0; i < CHUNK / 256; ++i) {
    int e = base + i * 256 + threadIdx.x;
    if (e >= E) continue;
    int d = dst[e];
    if (d < dlo || d >= dhi) continue;
    int s = src[e];
    float w = ew[e];
    int pos = __hip_atomic_fetch_add(&cnt[d], 1, __ATOMIC_RELAXED, __HIP_MEMORY_SCOPE_AGENT);
    if (pos < CAP)   // statistically unreachable; guards memory safety
      ell[(size_t)d * CAP + pos] = ell_pack(s, w);
  }
}

// ---------------- degcast + per-row bitonic sort by src ----------------
// Sorting each row ascending-by-src makes all concurrent waves in the
// aggregate kernels walk the src space monotonically -> gathers hit a
// narrow L2-resident band instead of the full 12.8 MB table.
__global__ __launch_bounds__(256) void k_degcast(const float* __restrict__ x,
                                                 const int* __restrict__ cnt,
                                                 unsigned* __restrict__ ell,
                                                 float* __restrict__ dinv,
                                                 unsigned* __restrict__ bhs) {
  int node = blockIdx.x * 4 + (threadIdx.x >> 6);
  if (node >= N) return;
  int lane = threadIdx.x & 63;

  int len = min(cnt[node], CAP);
  unsigned* rowp = ell + (size_t)node * CAP;
  unsigned v = (lane < len) ? rowp[lane] : 0xFFFFFFFFu;   // invalid -> src=0xFFFF sorts last

  // 64-lane bitonic sort, ascending by (v & 0xFFFF), full-word tie-break
#pragma unroll
  for (int k = 2; k <= 64; k <<= 1) {
#pragma unroll
    for (int j = k >> 1; j > 0; j >>= 1) {
      unsigned o = (unsigned)__shfl_xor((int)v, j, 64);
      unsigned vk = v & 0xFFFFu, ok = o & 0xFFFFu;
      bool vSmall = (vk < ok) || (vk == ok && v < o);
      bool keepSmall = ((lane & j) == 0) == ((lane & k) == 0);
      v = (vSmall == keepSmall) ? v : o;
    }
  }
  if (lane < len) rowp[lane] = v;

  float sum = (lane < len) ? ell_w(v) : 0.f;
#pragma unroll
  for (int off = 1; off < 64; off <<= 1) sum += __shfl_xor(sum, off, 64);

  float dv = 1.0f / sqrtf(1.0f + sum);
  if (lane == 0) dinv[node] = dv;

  float2 xv = ((const float2*)x)[(size_t)node * 64 + lane];
  bhs[(size_t)node * 64 + lane] = pack_bf16(xv.x * dv, xv.y * dv);
}

// ---------------- aggregation core (bf16 scaled gather, fp32 accumulate) ----------------
__device__ __forceinline__ float2 agg_core(const unsigned* __restrict__ bp,
                                           const unsigned* __restrict__ ell,
                                           int node, int len, float s) {
  unsigned hb = bp[(size_t)node * 64];
  float ax = blo(hb), ay = bhi(hb);

  const unsigned* row = ell + (size_t)node * CAP;
  int e = 0;
  for (; e + 8 <= len; e += 8) {
    uint4 p0 = *(const uint4*)(row + e);
    uint4 p1 = *(const uint4*)(row + e + 4);
    unsigned b0 = bp[(size_t)(p0.x & 0xFFFFu) * 64];
    unsigned b1 = bp[(size_t)(p0.y & 0xFFFFu) * 64];
    unsigned b2 = bp[(size_t)(p0.z & 0xFFFFu) * 64];
    unsigned b3 = bp[(size_t)(p0.w & 0xFFFFu) * 64];
    unsigned b4 = bp[(size_t)(p1.x & 0xFFFFu) * 64];
    unsigned b5 = bp[(size_t)(p1.y & 0xFFFFu) * 64];
    unsigned b6 = bp[(size_t)(p1.z & 0xFFFFu) * 64];
    unsigned b7 = bp[(size_t)(p1.w & 0xFFFFu) * 64];
    float w0 = ell_w(p0.x), w1 = ell_w(p0.y), w2 = ell_w(p0.z), w3 = ell_w(p0.w);
    float w4 = ell_w(p1.x), w5 = ell_w(p1.y), w6 = ell_w(p1.z), w7 = ell_w(p1.w);
    ax = fmaf(blo(b0), w0, ax); ay = fmaf(bhi(b0), w0, ay);
    ax = fmaf(blo(b1), w1, ax); ay = fmaf(bhi(b1), w1, ay);
    ax = fmaf(blo(b2), w2, ax); ay = fmaf(bhi(b2), w2, ay);
    ax = fmaf(blo(b3), w3, ax); ay = fmaf(bhi(b3), w3, ay);
    ax = fmaf(blo(b4), w4, ax); ay = fmaf(bhi(b4), w4, ay);
    ax = fmaf(blo(b5), w5, ax); ay = fmaf(bhi(b5), w5, ay);
    ax = fmaf(blo(b6), w6, ax); ay = fmaf(bhi(b6), w6, ay);
    ax = fmaf(blo(b7), w7, ax); ay = fmaf(bhi(b7), w7, ay);
  }
  if (e + 4 <= len) {
    uint4 p0 = *(const uint4*)(row + e);
    unsigned b0 = bp[(size_t)(p0.x & 0xFFFFu) * 64];
    unsigned b1 = bp[(size_t)(p0.y & 0xFFFFu) * 64];
    unsigned b2 = bp[(size_t)(p0.z & 0xFFFFu) * 64];
    unsigned b3 = bp[(size_t)(p0.w & 0xFFFFu) * 64];
    float w0 = ell_w(p0.x), w1 = ell_w(p0.y), w2 = ell_w(p0.z), w3 = ell_w(p0.w);
    ax = fmaf(blo(b0), w0, ax); ay = fmaf(bhi(b0), w0, ay);
    ax = fmaf(blo(b1), w1, ax); ay = fmaf(bhi(b1), w1, ay);
    ax = fmaf(blo(b2), w2, ax); ay = fmaf(bhi(b2), w2, ay);
    ax = fmaf(blo(b3), w3, ax); ay = fmaf(bhi(b3), w3, ay);
    e += 4;
  }
  for (; e < len; ++e) {
    unsigned pe = row[e];
    float w = ell_w(pe);
    unsigned b = bp[(size_t)(pe & 0xFFFFu) * 64];
    ax = fmaf(blo(b), w, ax); ay = fmaf(bhi(b), w, ay);
  }
  float2 r; r.x = ax * s; r.y = ay * s;
  return r;
}

// ---------------- fused layer: aggregate 64 nodes -> LDS -> MFMA -> bf16 out ----------------
__global__ __launch_bounds__(1024) void k_layer_fused(const unsigned* __restrict__ bhs,
                                                      const int* __restrict__ cnt,
                                                      const unsigned* __restrict__ ell,
                                                      const float* __restrict__ dinv,
                                                      const float* __restrict__ W,
                                                      const float* __restrict__ bias,
                                                      unsigned* __restrict__ outb) {
  __shared__ __align__(16) unsigned Al[64][68];   // 64 rows x 64 uints (+4 pad)
  __shared__ __align__(16) unsigned Wt[128][72];  // 128 cols x 64 uints (+8 pad)
  const int tid = threadIdx.x;
  const int row0 = blockIdx.x * 64;

  {  // stage W transposed+bf16: Wt[col][k2] = (W[2k2][col], W[2k2+1][col])
    int col = tid & 127, seg = tid >> 7;   // 8 segs x 8 words
#pragma unroll
    for (int m = 0; m < 8; ++m) {
      int k2 = seg * 8 + m;
      float w0 = W[(size_t)(2 * k2) * 128 + col];
      float w1 = W[(size_t)(2 * k2 + 1) * 128 + col];
      Wt[col][k2] = pack_bf16(w0, w1);
    }
  }

  const int w = tid >> 6, l = tid & 63;
#pragma unroll 1
  for (int i = 0; i < 4; ++i) {           // aggregate this wave's 4 nodes
    int r = 4 * w + i;
    int node = row0 + r;
    unsigned val = 0u;
    if (node < N) {
      float2 rr = agg_core(bhs + l, ell, node, cnt[node], dinv[node]);
      val = pack_bf16(rr.x, rr.y);
    }
    Al[r][l] = val;
  }
  __syncthreads();

  // MFMA: 32 tiles (4 row-tiles x 8 col-tiles), 2 per wave
  const int c = l & 15, q = l >> 4;
#pragma unroll
  for (int t2 = 0; t2 < 2; ++t2) {
    int t = 2 * w + t2;
    int rt = t >> 3, ct = t & 7;
    f32x4 acc = {};
#pragma unroll
    for (int ks = 0; ks < 4; ++ks) {
      bf16x8 af = *(const bf16x8*)&Al[rt * 16 + c][ks * 16 + 4 * q];
      bf16x8 bf = *(const bf16x8*)&Wt[ct * 16 + c][ks * 16 + 4 * q];
      acc = __builtin_amdgcn_mfma_f32_16x16x32_bf16(af, bf, acc, 0, 0, 0);
    }
    int col = ct * 16 + c;
    float bb = bias[col];
#pragma unroll
    for (int j = 0; j < 4; ++j) {
      int row = row0 + rt * 16 + 4 * q + j;
      float v = 0.f;
      if (row < N) v = fmaxf(acc[j] + bb, 0.f) * dinv[row];
      float o = __shfl_xor(v, 1);
      if (((c & 1) == 0) && row < N)
        outb[(size_t)row * 64 + (col >> 1)] = pack_bf16(v, o);
    }
  }
}

// ---------------- fused head: aggregate -> LDS -> dual MFMA -> fp32 mu/std ----------------
__global__ __launch_bounds__(1024) void k_head_fused(const unsigned* __restrict__ bhs,
                                                     const int* __restrict__ cnt,
                                                     const unsigned* __restrict__ ell,
                                                     const float* __restrict__ dinv,
                                                     const float* __restrict__ Wmu,
                                                     const float* __restrict__ Wstd,
                                                     const float* __restrict__ bmu,
                                                     const float* __restrict__ bstd,
                                                     float* __restrict__ out) {
  __shared__ __align__(16) unsigned Al[64][68];
  __shared__ __align__(16) unsigned Wt[128][72];
  const int tid = threadIdx.x;
  const int row0 = blockIdx.x * 64;

  {  // Wt = [Wmu | Wstd] transposed+bf16
    int col = tid & 127, seg = tid >> 7;
    const float* base = (col < DO) ? Wmu : Wstd;
    int cc = (col < DO) ? col : (col - DO);
#pragma unroll
    for (int m = 0; m < 8; ++m) {
      int k2 = seg * 8 + m;
      float w0 = base[(size_t)(2 * k2) * DO + cc];
      float w1 = base[(size_t)(2 * k2 + 1) * DO + cc];
      Wt[col][k2] = pack_bf16(w0, w1);
    }
  }

  const int w = tid >> 6, l = tid & 63;
#pragma unroll 1
  for (int i = 0; i < 4; ++i) {
    int r = 4 * w + i;
    int node = row0 + r;
    unsigned val = 0u;
    if (node < N) {
      float2 rr = agg_core(bhs + l, ell, node, cnt[node], dinv[node]);
      val = pack_bf16(rr.x, rr.y);
    }
    Al[r][l] = val;
  }
  __syncthreads();

  const int c = l & 15, q = l >> 4;
#pragma unroll
  for (int t2 = 0; t2 < 2; ++t2) {
    int t = 2 * w + t2;
    int rt = t >> 3, ct = t & 7;
    f32x4 acc = {};
#pragma unroll
    for (int ks = 0; ks < 4; ++ks) {
      bf16x8 af = *(const bf16x8*)&Al[rt * 16 + c][ks * 16 + 4 * q];
      bf16x8 bf = *(const bf16x8*)&Wt[ct * 16 + c][ks * 16 + 4 * q];
      acc = __builtin_amdgcn_mfma_f32_16x16x32_bf16(af, bf, acc, 0, 0, 0);
    }
    int col = ct * 16 + c;
    const bool is_mu = (col < DO);
    float bb = is_mu ? bmu[col] : bstd[col - DO];
    float* base = is_mu ? out : (out + (size_t)N * DO);
    int cc = is_mu ? col : (col - DO);
#pragma unroll
    for (int j = 0; j < 4; ++j) {
      int row = row0 + rt * 16 + 4 * q + j;
      if (row < N) base[(size_t)row * DO + cc] = acc[j] + bb;
    }
  }
}

// ---------------- launcher ----------------

static inline char* align256(char* p) {
  return (char*)(((uintptr_t)p + 255) & ~(uintptr_t)255);
}

extern "C" void kernel_launch(void* const* d_in, const int* in_sizes, int n_in,
                              void* d_out, int out_size, void* d_ws, size_t ws_size,
                              hipStream_t stream) {
  const float* x    = (const float*)d_in[0];
  const int*   ei   = (const int*)d_in[1];     // [2, E] int32
  const float* ew   = (const float*)d_in[2];
  const float* W1   = (const float*)d_in[3];
  const float* b1   = (const float*)d_in[4];
  const float* W2   = (const float*)d_in[5];
  const float* b2   = (const float*)d_in[6];
  const float* Wmu  = (const float*)d_in[7];
  const float* bmu  = (const float*)d_in[8];
  const float* Wstd = (const float*)d_in[9];
  const float* bstd = (const float*)d_in[10];
  float* out = (float*)d_out;

  const int* srcI = ei;
  const int* dstI = ei + E;

  char* p = (char*)d_ws;
  float*    dinv = (float*)p;     p = align256(p + (size_t)N * 4);
  int*      cnt  = (int*)p;       p = align256(p + (size_t)N * 4);
  unsigned* ell  = (unsigned*)p;  p = align256(p + (size_t)N * CAP * 4);  // 12.8 MB
  unsigned* bhs  = (unsigned*)p;  p = align256(p + (size_t)N * 64 * 4);   // 12.8 MB
  unsigned* bh2  = (unsigned*)p;  p = align256(p + (size_t)N * 64 * 4);   // 12.8 MB

  dim3 blk(256);
  const int gN     = (N + 255) / 256;
  const int nChunk = (E + CHUNK - 1) / CHUNK;     // 391
  const int gBuild = nChunk * NXCD;               // 3128
  const int gAgg   = (N + 3) / 4;
  const int gFuse  = (N + 63) / 64;               // 782

  // graph precompute: zero -> XCD-partitioned ELL build -> sort+deg/dinv/cast
  k_zero<<<gN, blk, 0, stream>>>(cnt);
  k_build_ell<<<gBuild, blk, 0, stream>>>(srcI, dstI, ew, cnt, ell);
  k_degcast<<<gAgg, blk, 0, stream>>>(x, cnt, ell, dinv, bhs);

  // layer 1: bhs -> bh2
  k_layer_fused<<<gFuse, dim3(1024), 0, stream>>>(bhs, cnt, ell, dinv, W1, b1, bh2);
  // layer 2: bh2 -> bhs
  k_layer_fused<<<gFuse, dim3(1024), 0, stream>>>(bh2, cnt, ell, dinv, W2, b2, bhs);
  // head: bhs -> out (mu, std)
  k_head_fused<<<gFuse, dim3(1024), 0, stream>>>(bhs, cnt, ell, dinv, Wmu, Wstd, bmu, bstd, out);
}

// Round 19
// 192.863 us; speedup vs baseline: 1.0281x; 1.0281x over previous
//
#include <hip/hip_runtime.h>
#include <hip/hip_fp16.h>
#include <math.h>

static constexpr int N = 50000;    // < 65536 -> src fits u16
static constexpr int E = 800000;
static constexpr int D = 128;      // D_IN = D_HID
static constexpr int DO = 64;      // D_OUT
static constexpr int CAP = 64;     // ELL row capacity (Poisson(16); P(deg>64) ~ 1e-26)
static constexpr int NXCD = 8;
static constexpr int DPX = 6272;   // dst range per XCD slot (8*6272 >= N)
static constexpr int CHUNK = 2048; // edges per workgroup chunk

// ---- bf16 helpers ----
__device__ __forceinline__ unsigned pack_bf16(float a, float b) {
  unsigned ua = __float_as_uint(a), ub = __float_as_uint(b);
  ua = (ua + 0x7FFFu + ((ua >> 16) & 1u)) >> 16;
  ub = (ub + 0x7FFFu + ((ub >> 16) & 1u)) >> 16;
  return ua | (ub << 16);
}
__device__ __forceinline__ float blo(unsigned u) { return __uint_as_float(u << 16); }
__device__ __forceinline__ float bhi(unsigned u) { return __uint_as_float(u & 0xFFFF0000u); }

// ---- ELL entry: low16 = src (u16), high16 = fp16 bits of raw ew ----
__device__ __forceinline__ unsigned ell_pack(int s, float w) {
  return (unsigned)s | ((unsigned)__half_as_ushort(__float2half(w)) << 16);
}
__device__ __forceinline__ float ell_w(unsigned p) {
  return __half2float(__ushort_as_half((unsigned short)(p >> 16)));
}

typedef __attribute__((ext_vector_type(8))) short bf16x8;
typedef __attribute__((ext_vector_type(4))) float f32x4;

// ---------------- zero per-dst counters ----------------
__global__ __launch_bounds__(256) void k_zero(int* __restrict__ cnt) {
  int i = blockIdx.x * 256 + threadIdx.x;
  if (i < N) cnt[i] = 0;
}

// ---------------- XCD-partitioned ELL build (R17, kept) ----------------
__global__ __launch_bounds__(256) void k_build_ell(const int* __restrict__ src,
                                                   const int* __restrict__ dst,
                                                   const float* __restrict__ ew,
                                                   int* __restrict__ cnt,
                                                   unsigned* __restrict__ ell) {
  const int xcd = blockIdx.x & (NXCD - 1);
  const int base = (blockIdx.x >> 3) * CHUNK;
  const int dlo = xcd * DPX, dhi = dlo + DPX;
#pragma unroll
  for (int i = 0; i < CHUNK / 256; ++i) {
    int e = base + i * 256 + threadIdx.x;
    if (e >= E) continue;
    int d = dst[e];
    if (d < dlo || d >= dhi) continue;
    int s = src[e];
    float w = ew[e];
    int pos = __hip_atomic_fetch_add(&cnt[d], 1, __ATOMIC_RELAXED, __HIP_MEMORY_SCOPE_AGENT);
    if (pos < CAP)   // statistically unreachable; guards memory safety
      ell[(size_t)d * CAP + pos] = ell_pack(s, w);
  }
}

// ---------------- deg -> dinv -> cast x to scaled bf16 (sort reverted) ----------------
__global__ __launch_bounds__(256) void k_degcast(const float* __restrict__ x,
                                                 const int* __restrict__ cnt,
                                                 const unsigned* __restrict__ ell,
                                                 float* __restrict__ dinv,
                                                 unsigned* __restrict__ bhs) {
  int node = blockIdx.x * 4 + (threadIdx.x >> 6);
  if (node >= N) return;
  int lane = threadIdx.x & 63;

  int len = cnt[node];
  float sum = (lane < len) ? ell_w(ell[(size_t)node * CAP + lane]) : 0.f;
#pragma unroll
  for (int off = 1; off < 64; off <<= 1) sum += __shfl_xor(sum, off, 64);

  float dv = 1.0f / sqrtf(1.0f + sum);
  if (lane == 0) dinv[node] = dv;

  float2 v = ((const float2*)x)[(size_t)node * 64 + lane];
  bhs[(size_t)node * 64 + lane] = pack_bf16(v.x * dv, v.y * dv);
}

// ---- 4-edge FMA helper ----
#define AGG4(P, AX, AY)                                                       \
  {                                                                           \
    unsigned g0 = bp[(size_t)((P).x & 0xFFFFu) * 64];                         \
    unsigned g1 = bp[(size_t)((P).y & 0xFFFFu) * 64];                         \
    unsigned g2 = bp[(size_t)((P).z & 0xFFFFu) * 64];                         \
    unsigned g3 = bp[(size_t)((P).w & 0xFFFFu) * 64];                         \
    float q0 = ell_w((P).x), q1 = ell_w((P).y), q2 = ell_w((P).z), q3 = ell_w((P).w); \
    AX = fmaf(blo(g0), q0, AX); AY = fmaf(bhi(g0), q0, AY);                   \
    AX = fmaf(blo(g1), q1, AX); AY = fmaf(bhi(g1), q1, AY);                   \
    AX = fmaf(blo(g2), q2, AX); AY = fmaf(bhi(g2), q2, AY);                   \
    AX = fmaf(blo(g3), q3, AX); AY = fmaf(bhi(g3), q3, AY);                   \
  }

// ---------------- pairwise aggregation: 2 nodes' chains interleaved ----------------
__device__ __forceinline__ void agg_pair(const unsigned* __restrict__ bp,
                                         const unsigned* __restrict__ ell,
                                         int node0, int len0, float s0,
                                         int node1, int len1, float s1,
                                         unsigned& out0, unsigned& out1) {
  unsigned h0 = bp[(size_t)node0 * 64];
  unsigned h1 = bp[(size_t)node1 * 64];
  float ax0 = blo(h0), ay0 = bhi(h0);
  float ax1 = blo(h1), ay1 = bhi(h1);
  const unsigned* rowA = ell + (size_t)node0 * CAP;
  const unsigned* rowB = ell + (size_t)node1 * CAP;

  int e0 = 0, e1 = 0;
  // interleaved main loop: 8 independent gathers across two chains
  while (e0 + 4 <= len0 && e1 + 4 <= len1) {
    uint4 pA = *(const uint4*)(rowA + e0);
    uint4 pB = *(const uint4*)(rowB + e1);
    unsigned a0 = bp[(size_t)(pA.x & 0xFFFFu) * 64];
    unsigned a1 = bp[(size_t)(pA.y & 0xFFFFu) * 64];
    unsigned a2 = bp[(size_t)(pA.z & 0xFFFFu) * 64];
    unsigned a3 = bp[(size_t)(pA.w & 0xFFFFu) * 64];
    unsigned b0 = bp[(size_t)(pB.x & 0xFFFFu) * 64];
    unsigned b1 = bp[(size_t)(pB.y & 0xFFFFu) * 64];
    unsigned b2 = bp[(size_t)(pB.z & 0xFFFFu) * 64];
    unsigned b3 = bp[(size_t)(pB.w & 0xFFFFu) * 64];
    float wa0 = ell_w(pA.x), wa1 = ell_w(pA.y), wa2 = ell_w(pA.z), wa3 = ell_w(pA.w);
    float wb0 = ell_w(pB.x), wb1 = ell_w(pB.y), wb2 = ell_w(pB.z), wb3 = ell_w(pB.w);
    ax0 = fmaf(blo(a0), wa0, ax0); ay0 = fmaf(bhi(a0), wa0, ay0);
    ax0 = fmaf(blo(a1), wa1, ax0); ay0 = fmaf(bhi(a1), wa1, ay0);
    ax0 = fmaf(blo(a2), wa2, ax0); ay0 = fmaf(bhi(a2), wa2, ay0);
    ax0 = fmaf(blo(a3), wa3, ax0); ay0 = fmaf(bhi(a3), wa3, ay0);
    ax1 = fmaf(blo(b0), wb0, ax1); ay1 = fmaf(bhi(b0), wb0, ay1);
    ax1 = fmaf(blo(b1), wb1, ax1); ay1 = fmaf(bhi(b1), wb1, ay1);
    ax1 = fmaf(blo(b2), wb2, ax1); ay1 = fmaf(bhi(b2), wb2, ay1);
    ax1 = fmaf(blo(b3), wb3, ax1); ay1 = fmaf(bhi(b3), wb3, ay1);
    e0 += 4; e1 += 4;
  }
  // drain row A
  for (; e0 + 4 <= len0; e0 += 4) { uint4 pA = *(const uint4*)(rowA + e0); AGG4(pA, ax0, ay0); }
  for (; e0 < len0; ++e0) {
    unsigned pe = rowA[e0];
    float w = ell_w(pe);
    unsigned g = bp[(size_t)(pe & 0xFFFFu) * 64];
    ax0 = fmaf(blo(g), w, ax0); ay0 = fmaf(bhi(g), w, ay0);
  }
  // drain row B
  for (; e1 + 4 <= len1; e1 += 4) { uint4 pB = *(const uint4*)(rowB + e1); AGG4(pB, ax1, ay1); }
  for (; e1 < len1; ++e1) {
    unsigned pe = rowB[e1];
    float w = ell_w(pe);
    unsigned g = bp[(size_t)(pe & 0xFFFFu) * 64];
    ax1 = fmaf(blo(g), w, ax1); ay1 = fmaf(bhi(g), w, ay1);
  }
  out0 = pack_bf16(ax0 * s0, ay0 * s0);
  out1 = pack_bf16(ax1 * s1, ay1 * s1);
}

// ---------------- fused layer: aggregate 64 nodes -> LDS -> MFMA -> bf16 out ----------------
__global__ __launch_bounds__(1024) void k_layer_fused(const unsigned* __restrict__ bhs,
                                                      const int* __restrict__ cnt,
                                                      const unsigned* __restrict__ ell,
                                                      const float* __restrict__ dinv,
                                                      const float* __restrict__ W,
                                                      const float* __restrict__ bias,
                                                      unsigned* __restrict__ outb) {
  __shared__ __align__(16) unsigned Al[64][68];   // 64 rows x 64 uints (+4 pad)
  __shared__ __align__(16) unsigned Wt[128][72];  // 128 cols x 64 uints (+8 pad)
  const int tid = threadIdx.x;
  const int row0 = blockIdx.x * 64;

  {  // stage W transposed+bf16: Wt[col][k2] = (W[2k2][col], W[2k2+1][col])
    int col = tid & 127, seg = tid >> 7;   // 8 segs x 8 words
#pragma unroll
    for (int m = 0; m < 8; ++m) {
      int k2 = seg * 8 + m;
      float w0 = W[(size_t)(2 * k2) * 128 + col];
      float w1 = W[(size_t)(2 * k2 + 1) * 128 + col];
      Wt[col][k2] = pack_bf16(w0, w1);
    }
  }

  const int w = tid >> 6, l = tid & 63;
  const unsigned* bp = bhs + l;
#pragma unroll
  for (int i = 0; i < 2; ++i) {           // 2 pairs per wave
    int r = 4 * w + 2 * i;
    int n0 = row0 + r, n1 = row0 + r + 1;
    unsigned v0 = 0u, v1 = 0u;
    if (n1 < N) {
      agg_pair(bp, ell, n0, cnt[n0], dinv[n0], n1, cnt[n1], dinv[n1], v0, v1);
    } else if (n0 < N) {
      unsigned dummy;
      agg_pair(bp, ell, n0, cnt[n0], dinv[n0], n0, 0, 0.f, v0, dummy);
    }
    Al[r][l] = v0;
    Al[r + 1][l] = v1;
  }
  __syncthreads();

  // MFMA: 32 tiles (4 row-tiles x 8 col-tiles), 2 per wave
  const int c = l & 15, q = l >> 4;
#pragma unroll
  for (int t2 = 0; t2 < 2; ++t2) {
    int t = 2 * w + t2;
    int rt = t >> 3, ct = t & 7;
    f32x4 acc = {};
#pragma unroll
    for (int ks = 0; ks < 4; ++ks) {
      bf16x8 af = *(const bf16x8*)&Al[rt * 16 + c][ks * 16 + 4 * q];
      bf16x8 bf = *(const bf16x8*)&Wt[ct * 16 + c][ks * 16 + 4 * q];
      acc = __builtin_amdgcn_mfma_f32_16x16x32_bf16(af, bf, acc, 0, 0, 0);
    }
    int col = ct * 16 + c;
    float bb = bias[col];
#pragma unroll
    for (int j = 0; j < 4; ++j) {
      int row = row0 + rt * 16 + 4 * q + j;
      float v = 0.f;
      if (row < N) v = fmaxf(acc[j] + bb, 0.f) * dinv[row];
      float o = __shfl_xor(v, 1);
      if (((c & 1) == 0) && row < N)
        outb[(size_t)row * 64 + (col >> 1)] = pack_bf16(v, o);
    }
  }
}

// ---------------- fused head: aggregate -> LDS -> dual MFMA -> fp32 mu/std ----------------
__global__ __launch_bounds__(1024) void k_head_fused(const unsigned* __restrict__ bhs,
                                                     const int* __restrict__ cnt,
                                                     const unsigned* __restrict__ ell,
                                                     const float* __restrict__ dinv,
                                                     const float* __restrict__ Wmu,
                                                     const float* __restrict__ Wstd,
                                                     const float* __restrict__ bmu,
                                                     const float* __restrict__ bstd,
                                                     float* __restrict__ out) {
  __shared__ __align__(16) unsigned Al[64][68];
  __shared__ __align__(16) unsigned Wt[128][72];
  const int tid = threadIdx.x;
  const int row0 = blockIdx.x * 64;

  {  // Wt = [Wmu | Wstd] transposed+bf16
    int col = tid & 127, seg = tid >> 7;
    const float* base = (col < DO) ? Wmu : Wstd;
    int cc = (col < DO) ? col : (col - DO);
#pragma unroll
    for (int m = 0; m < 8; ++m) {
      int k2 = seg * 8 + m;
      float w0 = base[(size_t)(2 * k2) * DO + cc];
      float w1 = base[(size_t)(2 * k2 + 1) * DO + cc];
      Wt[col][k2] = pack_bf16(w0, w1);
    }
  }

  const int w = tid >> 6, l = tid & 63;
  const unsigned* bp = bhs + l;
#pragma unroll
  for (int i = 0; i < 2; ++i) {
    int r = 4 * w + 2 * i;
    int n0 = row0 + r, n1 = row0 + r + 1;
    unsigned v0 = 0u, v1 = 0u;
    if (n1 < N) {
      agg_pair(bp, ell, n0, cnt[n0], dinv[n0], n1, cnt[n1], dinv[n1], v0, v1);
    } else if (n0 < N) {
      unsigned dummy;
      agg_pair(bp, ell, n0, cnt[n0], dinv[n0], n0, 0, 0.f, v0, dummy);
    }
    Al[r][l] = v0;
    Al[r + 1][l] = v1;
  }
  __syncthreads();

  const int c = l & 15, q = l >> 4;
#pragma unroll
  for (int t2 = 0; t2 < 2; ++t2) {
    int t = 2 * w + t2;
    int rt = t >> 3, ct = t & 7;
    f32x4 acc = {};
#pragma unroll
    for (int ks = 0; ks < 4; ++ks) {
      bf16x8 af = *(const bf16x8*)&Al[rt * 16 + c][ks * 16 + 4 * q];
      bf16x8 bf = *(const bf16x8*)&Wt[ct * 16 + c][ks * 16 + 4 * q];
      acc = __builtin_amdgcn_mfma_f32_16x16x32_bf16(af, bf, acc, 0, 0, 0);
    }
    int col = ct * 16 + c;
    const bool is_mu = (col < DO);
    float bb = is_mu ? bmu[col] : bstd[col - DO];
    float* base = is_mu ? out : (out + (size_t)N * DO);
    int cc = is_mu ? col : (col - DO);
#pragma unroll
    for (int j = 0; j < 4; ++j) {
      int row = row0 + rt * 16 + 4 * q + j;
      if (row < N) base[(size_t)row * DO + cc] = acc[j] + bb;
    }
  }
}

// ---------------- launcher ----------------

static inline char* align256(char* p) {
  return (char*)(((uintptr_t)p + 255) & ~(uintptr_t)255);
}

extern "C" void kernel_launch(void* const* d_in, const int* in_sizes, int n_in,
                              void* d_out, int out_size, void* d_ws, size_t ws_size,
                              hipStream_t stream) {
  const float* x    = (const float*)d_in[0];
  const int*   ei   = (const int*)d_in[1];     // [2, E] int32
  const float* ew   = (const float*)d_in[2];
  const float* W1   = (const float*)d_in[3];
  const float* b1   = (const float*)d_in[4];
  const float* W2   = (const float*)d_in[5];
  const float* b2   = (const float*)d_in[6];
  const float* Wmu  = (const float*)d_in[7];
  const float* bmu  = (const float*)d_in[8];
  const float* Wstd = (const float*)d_in[9];
  const float* bstd = (const float*)d_in[10];
  float* out = (float*)d_out;

  const int* srcI = ei;
  const int* dstI = ei + E;

  char* p = (char*)d_ws;
  float*    dinv = (float*)p;     p = align256(p + (size_t)N * 4);
  int*      cnt  = (int*)p;       p = align256(p + (size_t)N * 4);
  unsigned* ell  = (unsigned*)p;  p = align256(p + (size_t)N * CAP * 4);  // 12.8 MB
  unsigned* bhs  = (unsigned*)p;  p = align256(p + (size_t)N * 64 * 4);   // 12.8 MB
  unsigned* bh2  = (unsigned*)p;  p = align256(p + (size_t)N * 64 * 4);   // 12.8 MB

  dim3 blk(256);
  const int gN     = (N + 255) / 256;
  const int nChunk = (E + CHUNK - 1) / CHUNK;     // 391
  const int gBuild = nChunk * NXCD;               // 3128
  const int gAgg   = (N + 3) / 4;
  const int gFuse  = (N + 63) / 64;               // 782

  // graph precompute: zero -> XCD-partitioned ELL build -> deg/dinv/cast
  k_zero<<<gN, blk, 0, stream>>>(cnt);
  k_build_ell<<<gBuild, blk, 0, stream>>>(srcI, dstI, ew, cnt, ell);
  k_degcast<<<gAgg, blk, 0, stream>>>(x, cnt, ell, dinv, bhs);

  // layer 1: bhs -> bh2
  k_layer_fused<<<gFuse, dim3(1024), 0, stream>>>(bhs, cnt, ell, dinv, W1, b1, bh2);
  // layer 2: bh2 -> bhs
  k_layer_fused<<<gFuse, dim3(1024), 0, stream>>>(bh2, cnt, ell, dinv, W2, b2, bhs);
  // head: bhs -> out (mu, std)
  k_head_fused<<<gFuse, dim3(1024), 0, stream>>>(bhs, cnt, ell, dinv, Wmu, Wstd, bmu, bstd, out);
}

// Round 20
// 175.553 us; speedup vs baseline: 1.1295x; 1.0986x over previous
//
#include <hip/hip_runtime.h>
#include <hip/hip_fp16.h>
#include <math.h>

static constexpr int N = 50000;    // < 65536 -> src fits u16
static constexpr int E = 800000;
static constexpr int D = 128;      // D_IN = D_HID
static constexpr int DO = 64;      // D_OUT
static constexpr int CAP = 64;     // ELL row capacity (Poisson(16); P(deg>64) ~ 1e-26)
static constexpr int NXCD = 8;
static constexpr int DPX = 6272;   // dst range per XCD slot (8*6272 >= N)
static constexpr int CHUNK = 2048; // edges per workgroup chunk

// ---- bf16 helpers ----
__device__ __forceinline__ unsigned pack_bf16(float a, float b) {
  unsigned ua = __float_as_uint(a), ub = __float_as_uint(b);
  ua = (ua + 0x7FFFu + ((ua >> 16) & 1u)) >> 16;
  ub = (ub + 0x7FFFu + ((ub >> 16) & 1u)) >> 16;
  return ua | (ub << 16);
}
__device__ __forceinline__ float blo(unsigned u) { return __uint_as_float(u << 16); }
__device__ __forceinline__ float bhi(unsigned u) { return __uint_as_float(u & 0xFFFF0000u); }

// ---- ELL entry: low16 = src (u16), high16 = fp16 bits of raw ew ----
__device__ __forceinline__ unsigned ell_pack(int s, float w) {
  return (unsigned)s | ((unsigned)__half_as_ushort(__float2half(w)) << 16);
}
__device__ __forceinline__ float ell_w(unsigned p) {
  return __half2float(__ushort_as_half((unsigned short)(p >> 16)));
}

typedef __attribute__((ext_vector_type(8))) short bf16x8;
typedef __attribute__((ext_vector_type(4))) float f32x4;

// ---------------- zero per-dst counters ----------------
__global__ __launch_bounds__(256) void k_zero(int* __restrict__ cnt) {
  int i = blockIdx.x * 256 + threadIdx.x;
  if (i < N) cnt[i] = 0;
}

// ---------------- XCD-partitioned ELL build (R17, kept) ----------------
__global__ __launch_bounds__(256) void k_build_ell(const int* __restrict__ src,
                                                   const int* __restrict__ dst,
                                                   const float* __restrict__ ew,
                                                   int* __restrict__ cnt,
                                                   unsigned* __restrict__ ell) {
  const int xcd = blockIdx.x & (NXCD - 1);
  const int base = (blockIdx.x >> 3) * CHUNK;
  const int dlo = xcd * DPX, dhi = dlo + DPX;
#pragma unroll
  for (int i = 0; i < CHUNK / 256; ++i) {
    int e = base + i * 256 + threadIdx.x;
    if (e >= E) continue;
    int d = dst[e];
    if (d < dlo || d >= dhi) continue;
    int s = src[e];
    float w = ew[e];
    int pos = __hip_atomic_fetch_add(&cnt[d], 1, __ATOMIC_RELAXED, __HIP_MEMORY_SCOPE_AGENT);
    if (pos < CAP)   // statistically unreachable; guards memory safety
      ell[(size_t)d * CAP + pos] = ell_pack(s, w);
  }
}

// ---------------- deg -> dinv -> cast x to scaled bf16, one wave/node ----------------
__global__ __launch_bounds__(256) void k_degcast(const float* __restrict__ x,
                                                 const int* __restrict__ cnt,
                                                 const unsigned* __restrict__ ell,
                                                 float* __restrict__ dinv,
                                                 unsigned* __restrict__ bhs) {
  int node = blockIdx.x * 4 + (threadIdx.x >> 6);
  if (node >= N) return;
  int lane = threadIdx.x & 63;

  int len = cnt[node];
  float sum = (lane < len) ? ell_w(ell[(size_t)node * CAP + lane]) : 0.f;
#pragma unroll
  for (int off = 1; off < 64; off <<= 1) sum += __shfl_xor(sum, off, 64);

  float dv = 1.0f / sqrtf(1.0f + sum);
  if (lane == 0) dinv[node] = dv;

  float2 v = ((const float2*)x)[(size_t)node * 64 + lane];
  bhs[(size_t)node * 64 + lane] = pack_bf16(v.x * dv, v.y * dv);
}

// ---------------- aggregation core (bf16 scaled gather, fp32 accumulate) ----------------
// node/len/s are wave-uniform scalars (callers hoist via readfirstlane)
__device__ __forceinline__ float2 agg_core(const unsigned* __restrict__ bp,
                                           const unsigned* __restrict__ ell,
                                           int node, int len, float s) {
  unsigned hb = bp[(size_t)node * 64];
  float ax = blo(hb), ay = bhi(hb);

  const unsigned* row = ell + (size_t)node * CAP;
  int e = 0;
  for (; e + 8 <= len; e += 8) {
    uint4 p0 = *(const uint4*)(row + e);
    uint4 p1 = *(const uint4*)(row + e + 4);
    unsigned b0 = bp[(size_t)(p0.x & 0xFFFFu) * 64];
    unsigned b1 = bp[(size_t)(p0.y & 0xFFFFu) * 64];
    unsigned b2 = bp[(size_t)(p0.z & 0xFFFFu) * 64];
    unsigned b3 = bp[(size_t)(p0.w & 0xFFFFu) * 64];
    unsigned b4 = bp[(size_t)(p1.x & 0xFFFFu) * 64];
    unsigned b5 = bp[(size_t)(p1.y & 0xFFFFu) * 64];
    unsigned b6 = bp[(size_t)(p1.z & 0xFFFFu) * 64];
    unsigned b7 = bp[(size_t)(p1.w & 0xFFFFu) * 64];
    float w0 = ell_w(p0.x), w1 = ell_w(p0.y), w2 = ell_w(p0.z), w3 = ell_w(p0.w);
    float w4 = ell_w(p1.x), w5 = ell_w(p1.y), w6 = ell_w(p1.z), w7 = ell_w(p1.w);
    ax = fmaf(blo(b0), w0, ax); ay = fmaf(bhi(b0), w0, ay);
    ax = fmaf(blo(b1), w1, ax); ay = fmaf(bhi(b1), w1, ay);
    ax = fmaf(blo(b2), w2, ax); ay = fmaf(bhi(b2), w2, ay);
    ax = fmaf(blo(b3), w3, ax); ay = fmaf(bhi(b3), w3, ay);
    ax = fmaf(blo(b4), w4, ax); ay = fmaf(bhi(b4), w4, ay);
    ax = fmaf(blo(b5), w5, ax); ay = fmaf(bhi(b5), w5, ay);
    ax = fmaf(blo(b6), w6, ax); ay = fmaf(bhi(b6), w6, ay);
    ax = fmaf(blo(b7), w7, ax); ay = fmaf(bhi(b7), w7, ay);
  }
  if (e + 4 <= len) {
    uint4 p0 = *(const uint4*)(row + e);
    unsigned b0 = bp[(size_t)(p0.x & 0xFFFFu) * 64];
    unsigned b1 = bp[(size_t)(p0.y & 0xFFFFu) * 64];
    unsigned b2 = bp[(size_t)(p0.z & 0xFFFFu) * 64];
    unsigned b3 = bp[(size_t)(p0.w & 0xFFFFu) * 64];
    float w0 = ell_w(p0.x), w1 = ell_w(p0.y), w2 = ell_w(p0.z), w3 = ell_w(p0.w);
    ax = fmaf(blo(b0), w0, ax); ay = fmaf(bhi(b0), w0, ay);
    ax = fmaf(blo(b1), w1, ax); ay = fmaf(bhi(b1), w1, ay);
    ax = fmaf(blo(b2), w2, ax); ay = fmaf(bhi(b2), w2, ay);
    ax = fmaf(blo(b3), w3, ax); ay = fmaf(bhi(b3), w3, ay);
    e += 4;
  }
  for (; e < len; ++e) {
    unsigned pe = row[e];
    float w = ell_w(pe);
    unsigned b = bp[(size_t)(pe & 0xFFFFu) * 64];
    ax = fmaf(blo(b), w, ax); ay = fmaf(bhi(b), w, ay);
  }
  float2 r; r.x = ax * s; r.y = ay * s;
  return r;
}

// ---------------- fused layer: aggregate 64 nodes -> LDS -> MFMA -> bf16 out ----------------
// block = 1024 threads = 16 waves; wave aggregates 4 nodes; then 2 MFMA tiles/wave
__global__ __launch_bounds__(1024) void k_layer_fused(const unsigned* __restrict__ bhs,
                                                      const int* __restrict__ cnt,
                                                      const unsigned* __restrict__ ell,
                                                      const float* __restrict__ dinv,
                                                      const float* __restrict__ W,
                                                      const float* __restrict__ bias,
                                                      unsigned* __restrict__ outb) {
  __shared__ __align__(16) unsigned Al[64][68];   // 64 rows x 64 uints (+4 pad)
  __shared__ __align__(16) unsigned Wt[128][72];  // 128 cols x 64 uints (+8 pad)
  const int tid = threadIdx.x;
  const int row0 = blockIdx.x * 64;

  {  // stage W transposed+bf16: Wt[col][k2] = (W[2k2][col], W[2k2+1][col])
    int col = tid & 127, seg = tid >> 7;   // 8 segs x 8 words
#pragma unroll
    for (int m = 0; m < 8; ++m) {
      int k2 = seg * 8 + m;
      float w0 = W[(size_t)(2 * k2) * 128 + col];
      float w1 = W[(size_t)(2 * k2 + 1) * 128 + col];
      Wt[col][k2] = pack_bf16(w0, w1);
    }
  }

  const int w = __builtin_amdgcn_readfirstlane(tid >> 6);  // wave id -> SGPR
  const int l = tid & 63;
  const unsigned* bp = bhs + l;
#pragma unroll 1
  for (int i = 0; i < 4; ++i) {           // aggregate this wave's 4 nodes
    int r = 4 * w + i;
    int node = row0 + r;                  // scalar: row ptr/cnt/dinv via SMEM
    unsigned val = 0u;
    if (node < N) {
      float2 rr = agg_core(bp, ell, node, cnt[node], dinv[node]);
      val = pack_bf16(rr.x, rr.y);
    }
    Al[r][l] = val;
  }
  __syncthreads();

  // MFMA: 32 tiles (4 row-tiles x 8 col-tiles), 2 per wave
  const int c = l & 15, q = l >> 4;
#pragma unroll
  for (int t2 = 0; t2 < 2; ++t2) {
    int t = 2 * w + t2;
    int rt = t >> 3, ct = t & 7;
    f32x4 acc = {};
#pragma unroll
    for (int ks = 0; ks < 4; ++ks) {
      bf16x8 af = *(const bf16x8*)&Al[rt * 16 + c][ks * 16 + 4 * q];
      bf16x8 bf = *(const bf16x8*)&Wt[ct * 16 + c][ks * 16 + 4 * q];
      acc = __builtin_amdgcn_mfma_f32_16x16x32_bf16(af, bf, acc, 0, 0, 0);
    }
    int col = ct * 16 + c;
    float bb = bias[col];
#pragma unroll
    for (int j = 0; j < 4; ++j) {
      int row = row0 + rt * 16 + 4 * q + j;
      float v = 0.f;
      if (row < N) v = fmaxf(acc[j] + bb, 0.f) * dinv[row];
      float o = __shfl_xor(v, 1);
      if (((c & 1) == 0) && row < N)
        outb[(size_t)row * 64 + (col >> 1)] = pack_bf16(v, o);
    }
  }
}

// ---------------- fused head: aggregate -> LDS -> dual MFMA -> fp32 mu/std ----------------
__global__ __launch_bounds__(1024) void k_head_fused(const unsigned* __restrict__ bhs,
                                                     const int* __restrict__ cnt,
                                                     const unsigned* __restrict__ ell,
                                                     const float* __restrict__ dinv,
                                                     const float* __restrict__ Wmu,
                                                     const float* __restrict__ Wstd,
                                                     const float* __restrict__ bmu,
                                                     const float* __restrict__ bstd,
                                                     float* __restrict__ out) {
  __shared__ __align__(16) unsigned Al[64][68];
  __shared__ __align__(16) unsigned Wt[128][72];
  const int tid = threadIdx.x;
  const int row0 = blockIdx.x * 64;

  {  // Wt = [Wmu | Wstd] transposed+bf16
    int col = tid & 127, seg = tid >> 7;
    const float* base = (col < DO) ? Wmu : Wstd;
    int cc = (col < DO) ? col : (col - DO);
#pragma unroll
    for (int m = 0; m < 8; ++m) {
      int k2 = seg * 8 + m;
      float w0 = base[(size_t)(2 * k2) * DO + cc];
      float w1 = base[(size_t)(2 * k2 + 1) * DO + cc];
      Wt[col][k2] = pack_bf16(w0, w1);
    }
  }

  const int w = __builtin_amdgcn_readfirstlane(tid >> 6);
  const int l = tid & 63;
  const unsigned* bp = bhs + l;
#pragma unroll 1
  for (int i = 0; i < 4; ++i) {
    int r = 4 * w + i;
    int node = row0 + r;
    unsigned val = 0u;
    if (node < N) {
      float2 rr = agg_core(bp, ell, node, cnt[node], dinv[node]);
      val = pack_bf16(rr.x, rr.y);
    }
    Al[r][l] = val;
  }
  __syncthreads();

  const int c = l & 15, q = l >> 4;
#pragma unroll
  for (int t2 = 0; t2 < 2; ++t2) {
    int t = 2 * w + t2;
    int rt = t >> 3, ct = t & 7;
    f32x4 acc = {};
#pragma unroll
    for (int ks = 0; ks < 4; ++ks) {
      bf16x8 af = *(const bf16x8*)&Al[rt * 16 + c][ks * 16 + 4 * q];
      bf16x8 bf = *(const bf16x8*)&Wt[ct * 16 + c][ks * 16 + 4 * q];
      acc = __builtin_amdgcn_mfma_f32_16x16x32_bf16(af, bf, acc, 0, 0, 0);
    }
    int col = ct * 16 + c;
    const bool is_mu = (col < DO);
    float bb = is_mu ? bmu[col] : bstd[col - DO];
    float* base = is_mu ? out : (out + (size_t)N * DO);
    int cc = is_mu ? col : (col - DO);
#pragma unroll
    for (int j = 0; j < 4; ++j) {
      int row = row0 + rt * 16 + 4 * q + j;
      if (row < N) base[(size_t)row * DO + cc] = acc[j] + bb;
    }
  }
}

// ---------------- launcher ----------------

static inline char* align256(char* p) {
  return (char*)(((uintptr_t)p + 255) & ~(uintptr_t)255);
}

extern "C" void kernel_launch(void* const* d_in, const int* in_sizes, int n_in,
                              void* d_out, int out_size, void* d_ws, size_t ws_size,
                              hipStream_t stream) {
  const float* x    = (const float*)d_in[0];
  const int*   ei   = (const int*)d_in[1];     // [2, E] int32
  const float* ew   = (const float*)d_in[2];
  const float* W1   = (const float*)d_in[3];
  const float* b1   = (const float*)d_in[4];
  const float* W2   = (const float*)d_in[5];
  const float* b2   = (const float*)d_in[6];
  const float* Wmu  = (const float*)d_in[7];
  const float* bmu  = (const float*)d_in[8];
  const float* Wstd = (const float*)d_in[9];
  const float* bstd = (const float*)d_in[10];
  float* out = (float*)d_out;

  const int* srcI = ei;
  const int* dstI = ei + E;

  char* p = (char*)d_ws;
  float*    dinv = (float*)p;     p = align256(p + (size_t)N * 4);
  int*      cnt  = (int*)p;       p = align256(p + (size_t)N * 4);
  unsigned* ell  = (unsigned*)p;  p = align256(p + (size_t)N * CAP * 4);  // 12.8 MB
  unsigned* bhs  = (unsigned*)p;  p = align256(p + (size_t)N * 64 * 4);   // 12.8 MB
  unsigned* bh2  = (unsigned*)p;  p = align256(p + (size_t)N * 64 * 4);   // 12.8 MB

  dim3 blk(256);
  const int gN     = (N + 255) / 256;
  const int nChunk = (E + CHUNK - 1) / CHUNK;     // 391
  const int gBuild = nChunk * NXCD;               // 3128
  const int gAgg   = (N + 3) / 4;
  const int gFuse  = (N + 63) / 64;               // 782

  // graph precompute: zero -> XCD-partitioned ELL build -> deg/dinv/cast
  k_zero<<<gN, blk, 0, stream>>>(cnt);
  k_build_ell<<<gBuild, blk, 0, stream>>>(srcI, dstI, ew, cnt, ell);
  k_degcast<<<gAgg, blk, 0, stream>>>(x, cnt, ell, dinv, bhs);

  // layer 1: bhs -> bh2
  k_layer_fused<<<gFuse, dim3(1024), 0, stream>>>(bhs, cnt, ell, dinv, W1, b1, bh2);
  // layer 2: bh2 -> bhs
  k_layer_fused<<<gFuse, dim3(1024), 0, stream>>>(bh2, cnt, ell, dinv, W2, b2, bhs);
  // head: bhs -> out (mu, std)
  k_head_fused<<<gFuse, dim3(1024), 0, stream>>>(bhs, cnt, ell, dinv, Wmu, Wstd, bmu, bstd, out);
}